// Round 14
// baseline (79.697 us; speedup 1.0000x reference)
//
#include <hip/hip_runtime.h>

// Pfaffian of 128 gathered 128x128 skew-symmetric f32 matrices, Parlett-Reid
// LTL^T. One 512-thread block per matrix. Look-ahead panel pipeline (crew
// wave computes panel P+1 tau/col while bulk waves apply panel P; one
// barrier per window) + PACKED fp32 FMAs (v_pk_fma_f32 via
// __builtin_elementwise_fma on float2 vectors — each half is an independent
// IEEE-rn fma, so the f32 trajectory is bit-identical to rounds 5-13).
//
// NUMERICS LEDGER (rounds 0-13): np ref is the XLA-CPU f32 trajectory:
//     tmp = fma(tau_r, col_c, A);  A' = fma(-col_r, tau_c, tmp)
// tau = __fdiv_rn(row_k, piv), pf = __fmul_rn in step order. Rounds 5-13
// PASSED with absmax 0.0234375 (bit-stable fingerprint). Dead indices are
// staged/published as exact 0.0f -> identity FMAs on never-read entries.
//
// PERF LEDGER: r8 static idx 50.6us -> r9 47 -> r11 512thr 41 -> r12 panels
// ~29 -> r13 look-ahead ~25.6us. r13 window ~3500cyc: bulk scalar-FMA issue
// (256 insts/wave/window) is a first-order term. r14: pack bulk (32 pk-fma
// /step) and crew chain -> bulk issue halves; crew pole shortens.

typedef float v2f __attribute__((ext_vector_type(2)));
#define FMA2(a, b, c) __builtin_elementwise_fma((a), (b), (c))
#define RL(v, l) __int_as_float(__builtin_amdgcn_readlane(__float_as_int(v), (l)))

static __device__ __forceinline__ v2f splat2(float s) { v2f r; r.x = s; r.y = s; return r; }

__global__ __launch_bounds__(512) void pfaffian_kernel(
    const float* __restrict__ x,    // [128, 128]
    const float* __restrict__ F,    // [32640] packed strict lower tri of 256x256
    float* __restrict__ out)        // [128]
{
    const int b    = blockIdx.x;
    const int t    = threadIdx.x;
    const int lane = t & 63;
    const int wave = t >> 6;        // 0..7

    __shared__ int idx_sh[128];
    __shared__ int wtot[4];
    __shared__ __align__(16) float tauLDS[2][4][128];
    __shared__ __align__(16) float colLDS[2][4][128];
    __shared__ __align__(16) float rS[2][4][128];   // panel row vecs k0,k0+2,k0+4,k0+6
    __shared__ __align__(16) float cS[2][4][128];   // panel col vecs k0+1,+3,+5,+7

    // ---- occupancy -> sorted index list (certified r0-r13) ----
    if (t < 256) {
        const float xv  = x[b * 128 + (t & 127)];
        const bool  pos = xv > 0.0f;
        const bool  o   = (t < 128) ? pos : !pos;
        const unsigned long long mm = __ballot(o);
        const int rank = __popcll(mm & ((1ull << lane) - 1ull));
        if (lane == 63) wtot[wave] = rank + (o ? 1 : 0);
        __syncthreads();
        int off = 0;
#pragma unroll
        for (int w = 0; w < 4; ++w)
            if (w < wave) off += wtot[w];
        if (o) idx_sh[off + rank] = t;
    } else {
        __syncthreads();   // matches the barrier inside the t<256 branch
    }
    __syncthreads();

    // ---- 4x8 block ownership; A packed as column pairs ----
    const int rg   = t >> 4;        // rows [rg*4, rg*4+4)
    const int cg   = t & 15;        // cols [cg*8, cg*8+8)
    const int row0 = rg << 2;
    const int col0 = cg << 3;

    int ri[4], ci[8];
#pragma unroll
    for (int a = 0; a < 4; ++a) ri[a] = idx_sh[row0 + a];
#pragma unroll
    for (int c = 0; c < 8; ++c) ci[c] = idx_sh[col0 + c];

    v2f A2[4][4];   // A2[a][c2] = {A[a][2c2], A[a][2c2+1]}
#pragma unroll
    for (int a = 0; a < 4; ++a) {
        const int ii = ri[a];
#pragma unroll
        for (int c2 = 0; c2 < 4; ++c2) {
            float e[2];
#pragma unroll
            for (int u = 0; u < 2; ++u) {
                const int jj = ci[2 * c2 + u];
                const int hi = ii > jj ? ii : jj;
                const int lo = ii > jj ? jj : ii;
                float v = (ii == jj) ? 0.0f : F[(hi * (hi - 1)) / 2 + lo];
                e[u] = (ii < jj) ? -v : v;
            }
            A2[a][c2].x = e[0]; A2[a][c2].y = e[1];
        }
    }

    // stage panel Pn (rows 8Pn..+6 even from rg 2Pn/2Pn+1, cols odd from cg Pn)
    auto stage = [&](int Pn, int st) {
        const int rgbase = 2 * Pn;
        if (rg == rgbase) {
            *(float4*)&rS[st][0][col0]     = make_float4(A2[0][0].x, A2[0][0].y, A2[0][1].x, A2[0][1].y);
            *(float4*)&rS[st][0][col0 + 4] = make_float4(A2[0][2].x, A2[0][2].y, A2[0][3].x, A2[0][3].y);
            *(float4*)&rS[st][1][col0]     = make_float4(A2[2][0].x, A2[2][0].y, A2[2][1].x, A2[2][1].y);
            *(float4*)&rS[st][1][col0 + 4] = make_float4(A2[2][2].x, A2[2][2].y, A2[2][3].x, A2[2][3].y);
        }
        if (rg == rgbase + 1) {
            *(float4*)&rS[st][2][col0]     = make_float4(A2[0][0].x, A2[0][0].y, A2[0][1].x, A2[0][1].y);
            *(float4*)&rS[st][2][col0 + 4] = make_float4(A2[0][2].x, A2[0][2].y, A2[0][3].x, A2[0][3].y);
            *(float4*)&rS[st][3][col0]     = make_float4(A2[2][0].x, A2[2][0].y, A2[2][1].x, A2[2][1].y);
            *(float4*)&rS[st][3][col0 + 4] = make_float4(A2[2][2].x, A2[2][2].y, A2[2][3].x, A2[2][3].y);
        }
        if (cg == Pn) {
            *(float4*)&cS[st][0][row0] = make_float4(A2[0][0].y, A2[1][0].y, A2[2][0].y, A2[3][0].y);
            *(float4*)&cS[st][1][row0] = make_float4(A2[0][1].y, A2[1][1].y, A2[2][1].y, A2[3][1].y);
            *(float4*)&cS[st][2][row0] = make_float4(A2[0][2].y, A2[1][2].y, A2[2][2].y, A2[3][2].y);
            *(float4*)&cS[st][3][row0] = make_float4(A2[0][3].y, A2[1][3].y, A2[2][3].y, A2[3][3].y);
        }
    };
    stage(0, 0);   // panel 0 raw
    stage(1, 1);   // panel 1 raw
    __syncthreads();

    float pf = 1.0f;
    v2f TAUp[4], CVp[4];   // crew: previous panel's tau/col (lane pair g0,g1)

    // crew for panel Pn: pre-update with panel Pn-1 (if pre), chain, publish
    auto crew = [&](int Pn, bool pre) {
        const int sv = Pn & 1;
        const int g0 = lane << 1;
        const int g1 = g0 + 1;
        v2f R[4], C[4];
#pragma unroll
        for (int j = 0; j < 4; ++j) {
            R[j] = *(const v2f*)&rS[sv][j][g0];
            C[j] = *(const v2f*)&cS[sv][j][g0];
        }
        if (pre) {
            // apply panel Pn-1 (TAUp/CVp) to these 8 vectors — packed, same
            // per-element fma pairs in step order as bulk (zeros -> identity)
#pragma unroll
            for (int jp = 0; jp < 4; ++jp) {
#pragma unroll
                for (int a = 0; a < 4; ++a) {
                    const int la = 4 * Pn + a;   // lane of row 8Pn+2a / col +1
                    const float tau_r = RL(TAUp[jp].x, la);
                    const float col_r = RL(CVp[jp].x, la);
                    R[a] = FMA2(splat2(-col_r), TAUp[jp],
                           FMA2(splat2(tau_r), CVp[jp], R[a]));
                    const float tau_c = RL(TAUp[jp].y, la);
                    const float col_c = RL(CVp[jp].y, la);
                    C[a] = FMA2(-CVp[jp], splat2(tau_c),
                           FMA2(TAUp[jp], splat2(col_c), C[a]));
                }
            }
        }
        v2f TAU[4], CV[4];
#pragma unroll
        for (int j = 0; j < 4; ++j) {
            const int k = 8 * Pn + 2 * j;
            const float piv = RL(R[j].y, 4 * Pn + j);
            pf = __fmul_rn(pf, piv);          // step order
            TAU[j].x = (g0 > k + 1) ? __fdiv_rn(R[j].x, piv) : 0.0f;
            TAU[j].y = (g1 > k + 1) ? __fdiv_rn(R[j].y, piv) : 0.0f;
            CV[j].x  = (g0 > k + 1) ? C[j].x : 0.0f;
            CV[j].y  = (g1 > k + 1) ? C[j].y : 0.0f;
            *(v2f*)&tauLDS[sv][j][g0] = TAU[j];
            *(v2f*)&colLDS[sv][j][g0] = CV[j];
            // look-ahead: update later panel vectors with step j
#pragma unroll
            for (int j2 = j + 1; j2 < 4; ++j2) {
                const int ls = 4 * Pn + j2;
                const float tau_r = RL(TAU[j].x, ls);
                const float col_r = RL(CV[j].x, ls);
                R[j2] = FMA2(splat2(-col_r), TAU[j],
                        FMA2(splat2(tau_r), CV[j], R[j2]));
                const float tau_c = RL(TAU[j].y, ls);
                const float col_c = RL(CV[j].y, ls);
                C[j2] = FMA2(-CV[j], splat2(tau_c),
                        FMA2(TAU[j], splat2(col_c), C[j2]));
            }
        }
#pragma unroll
        for (int j = 0; j < 4; ++j) { TAUp[j] = TAU[j]; CVp[j] = CV[j]; }
    };

    // ---- prologue: crew computes panel 0 from raw staged vectors ----
    if (wave == 0) crew(0, false);
    __syncthreads();

    // ---- 15 windows, ONE barrier each: bulk panel P || crew panel P+1 ----
    for (int P = 0; P < 15; ++P) {
        if (wave >= 1 && 2 * wave > P) {
            const int sp = P & 1;
#pragma unroll
            for (int j = 0; j < 4; ++j) {
                const float4 trv = *(const float4*)&tauLDS[sp][j][row0];
                const float4 crv = *(const float4*)&colLDS[sp][j][row0];
                const float4 t0v = *(const float4*)&tauLDS[sp][j][col0];
                const float4 t1v = *(const float4*)&tauLDS[sp][j][col0 + 4];
                const float4 c0v = *(const float4*)&colLDS[sp][j][col0];
                const float4 c1v = *(const float4*)&colLDS[sp][j][col0 + 4];
                const float tr[4] = {trv.x, trv.y, trv.z, trv.w};
                const float cr[4] = {crv.x, crv.y, crv.z, crv.w};
                v2f tc2[4], cc2[4];
                tc2[0].x = t0v.x; tc2[0].y = t0v.y; tc2[1].x = t0v.z; tc2[1].y = t0v.w;
                tc2[2].x = t1v.x; tc2[2].y = t1v.y; tc2[3].x = t1v.z; tc2[3].y = t1v.w;
                cc2[0].x = c0v.x; cc2[0].y = c0v.y; cc2[1].x = c0v.z; cc2[1].y = c0v.w;
                cc2[2].x = c1v.x; cc2[2].y = c1v.y; cc2[3].x = c1v.z; cc2[3].y = c1v.w;
#pragma unroll
                for (int a = 0; a < 4; ++a) {
                    const v2f trs  = splat2(tr[a]);
                    const v2f ncrs = splat2(-cr[a]);
#pragma unroll
                    for (int c2 = 0; c2 < 4; ++c2) {
                        A2[a][c2] = FMA2(ncrs, tc2[c2],
                                    FMA2(trs, cc2[c2], A2[a][c2]));
                    }
                }
            }
            if (P <= 13) stage(P + 2, P & 1);   // updated through P
        }
        if (wave == 0) crew(P + 1, true);       // panels 1..15
        __syncthreads();
    }

    if (t == 0) out[b] = pf;
}

extern "C" void kernel_launch(void* const* d_in, const int* in_sizes, int n_in,
                              void* d_out, int out_size, void* d_ws, size_t ws_size,
                              hipStream_t stream) {
    const float* x = (const float*)d_in[0];   // [128*128]
    const float* F = (const float*)d_in[1];   // [32640]
    float* out     = (float*)d_out;           // [128]
    (void)in_sizes; (void)n_in; (void)out_size; (void)d_ws; (void)ws_size;

    pfaffian_kernel<<<128, 512, 0, stream>>>(x, F, out);
}

// Round 15
// 77.272 us; speedup vs baseline: 1.0314x; 1.0314x over previous
//
#include <hip/hip_runtime.h>

// Pfaffian of 128 gathered 128x128 skew-symmetric f32 matrices, Parlett-Reid
// LTL^T. One 512-thread block per matrix. Look-ahead panel pipeline: crew
// (wave 0) computes panel P+1's tau/col while bulk (waves 1-7) applies
// panel P; ONE barrier per window, 15 windows.
//
// NUMERICS LEDGER (rounds 0-14): np ref is the XLA-CPU f32 trajectory:
//     tmp = fma(tau_r, col_c, A);  A' = fma(-col_r, tau_c, tmp)
// tau = __fdiv_rn(row_k, piv), pf = __fmul_rn in step order. Rounds 5-14
// PASSED with absmax 0.0234375 (bit-stable fingerprint). Dead indices are
// staged/published as exact 0.0f -> identity FMAs on never-read entries.
// Bulk uses v_pk_fma_f32 (each half independent IEEE-rn fma = bit-exact).
//
// PERF LEDGER: r8 50.6us -> r9 47 -> r11 41 -> r12 panels ~29 -> r13
// look-ahead ~25.6 -> r14 (pk everywhere) neutral/worse => crew is the
// window pole; packing hurt its serial chain. r15: crew reverted to r13
// scalar; pk kept in bulk only; bulk's 24 ds_read_b128 batched upfront
// (latencies overlap); s_setprio(3) on crew wave (shares SIMD0 with bulk
// wave 4 — priority shortens the pole). Bench floor note: ~50us of bench
// dur is the harness's 268MB ws re-poison, not kernel time.

typedef float v2f __attribute__((ext_vector_type(2)));
#define FMA2(a, b, c) __builtin_elementwise_fma((a), (b), (c))
#define RL(v, l) __int_as_float(__builtin_amdgcn_readlane(__float_as_int(v), (l)))

static __device__ __forceinline__ v2f splat2(float s) { v2f r; r.x = s; r.y = s; return r; }

__global__ __launch_bounds__(512) void pfaffian_kernel(
    const float* __restrict__ x,    // [128, 128]
    const float* __restrict__ F,    // [32640] packed strict lower tri of 256x256
    float* __restrict__ out)        // [128]
{
    const int b    = blockIdx.x;
    const int t    = threadIdx.x;
    const int lane = t & 63;
    const int wave = t >> 6;        // 0..7

    __shared__ int idx_sh[128];
    __shared__ int wtot[4];
    __shared__ __align__(16) float tauLDS[2][4][128];
    __shared__ __align__(16) float colLDS[2][4][128];
    __shared__ __align__(16) float rS[2][4][128];   // panel row vecs k0,k0+2,k0+4,k0+6
    __shared__ __align__(16) float cS[2][4][128];   // panel col vecs k0+1,+3,+5,+7

    // ---- occupancy -> sorted index list (certified r0-r14) ----
    if (t < 256) {
        const float xv  = x[b * 128 + (t & 127)];
        const bool  pos = xv > 0.0f;
        const bool  o   = (t < 128) ? pos : !pos;
        const unsigned long long mm = __ballot(o);
        const int rank = __popcll(mm & ((1ull << lane) - 1ull));
        if (lane == 63) wtot[wave] = rank + (o ? 1 : 0);
        __syncthreads();
        int off = 0;
#pragma unroll
        for (int w = 0; w < 4; ++w)
            if (w < wave) off += wtot[w];
        if (o) idx_sh[off + rank] = t;
    } else {
        __syncthreads();   // matches the barrier inside the t<256 branch
    }
    __syncthreads();

    if (wave == 0) __builtin_amdgcn_s_setprio(3);   // crew wins SIMD0 arbitration

    // ---- 4x8 block ownership; A packed as column pairs ----
    const int rg   = t >> 4;        // rows [rg*4, rg*4+4)
    const int cg   = t & 15;        // cols [cg*8, cg*8+8)
    const int row0 = rg << 2;
    const int col0 = cg << 3;

    int ri[4], ci[8];
#pragma unroll
    for (int a = 0; a < 4; ++a) ri[a] = idx_sh[row0 + a];
#pragma unroll
    for (int c = 0; c < 8; ++c) ci[c] = idx_sh[col0 + c];

    v2f A2[4][4];   // A2[a][c2] = {A[a][2c2], A[a][2c2+1]}
#pragma unroll
    for (int a = 0; a < 4; ++a) {
        const int ii = ri[a];
#pragma unroll
        for (int c2 = 0; c2 < 4; ++c2) {
            float e[2];
#pragma unroll
            for (int u = 0; u < 2; ++u) {
                const int jj = ci[2 * c2 + u];
                const int hi = ii > jj ? ii : jj;
                const int lo = ii > jj ? jj : ii;
                float v = (ii == jj) ? 0.0f : F[(hi * (hi - 1)) / 2 + lo];
                e[u] = (ii < jj) ? -v : v;
            }
            A2[a][c2].x = e[0]; A2[a][c2].y = e[1];
        }
    }

    // stage panel Pn (rows 8Pn..+6 even from rg 2Pn/2Pn+1, cols odd from cg Pn)
    auto stage = [&](int Pn, int st) {
        const int rgbase = 2 * Pn;
        if (rg == rgbase) {
            *(float4*)&rS[st][0][col0]     = make_float4(A2[0][0].x, A2[0][0].y, A2[0][1].x, A2[0][1].y);
            *(float4*)&rS[st][0][col0 + 4] = make_float4(A2[0][2].x, A2[0][2].y, A2[0][3].x, A2[0][3].y);
            *(float4*)&rS[st][1][col0]     = make_float4(A2[2][0].x, A2[2][0].y, A2[2][1].x, A2[2][1].y);
            *(float4*)&rS[st][1][col0 + 4] = make_float4(A2[2][2].x, A2[2][2].y, A2[2][3].x, A2[2][3].y);
        }
        if (rg == rgbase + 1) {
            *(float4*)&rS[st][2][col0]     = make_float4(A2[0][0].x, A2[0][0].y, A2[0][1].x, A2[0][1].y);
            *(float4*)&rS[st][2][col0 + 4] = make_float4(A2[0][2].x, A2[0][2].y, A2[0][3].x, A2[0][3].y);
            *(float4*)&rS[st][3][col0]     = make_float4(A2[2][0].x, A2[2][0].y, A2[2][1].x, A2[2][1].y);
            *(float4*)&rS[st][3][col0 + 4] = make_float4(A2[2][2].x, A2[2][2].y, A2[2][3].x, A2[2][3].y);
        }
        if (cg == Pn) {
            *(float4*)&cS[st][0][row0] = make_float4(A2[0][0].y, A2[1][0].y, A2[2][0].y, A2[3][0].y);
            *(float4*)&cS[st][1][row0] = make_float4(A2[0][1].y, A2[1][1].y, A2[2][1].y, A2[3][1].y);
            *(float4*)&cS[st][2][row0] = make_float4(A2[0][2].y, A2[1][2].y, A2[2][2].y, A2[3][2].y);
            *(float4*)&cS[st][3][row0] = make_float4(A2[0][3].y, A2[1][3].y, A2[2][3].y, A2[3][3].y);
        }
    };
    stage(0, 0);   // panel 0 raw
    stage(1, 1);   // panel 1 raw
    __syncthreads();

    float pf = 1.0f;
    float TAUp[4][2], CVp[4][2];   // crew: previous panel's tau/col (registers)

    // crew for panel Pn (r13-proven SCALAR form): pre-update with panel Pn-1
    // (if pre), chain the 4 steps, publish tau/col
    auto crew = [&](int Pn, bool pre) {
        const int sv = Pn & 1;
        const int g0 = lane << 1;
        const int g1 = g0 + 1;
        float R[4][2], C[4][2];
#pragma unroll
        for (int j = 0; j < 4; ++j) {
            const float2 rv = *(const float2*)&rS[sv][j][g0];
            const float2 cv = *(const float2*)&cS[sv][j][g0];
            R[j][0] = rv.x; R[j][1] = rv.y;
            C[j][0] = cv.x; C[j][1] = cv.y;
        }
        if (pre) {
#pragma unroll
            for (int jp = 0; jp < 4; ++jp) {
#pragma unroll
                for (int a = 0; a < 4; ++a) {
                    const int la = 4 * Pn + a;   // lane of row 8Pn+2a / col +1
                    const float tau_r = RL(TAUp[jp][0], la);
                    const float col_r = RL(CVp[jp][0], la);
                    R[a][0] = __fmaf_rn(-col_r, TAUp[jp][0],
                              __fmaf_rn(tau_r, CVp[jp][0], R[a][0]));
                    R[a][1] = __fmaf_rn(-col_r, TAUp[jp][1],
                              __fmaf_rn(tau_r, CVp[jp][1], R[a][1]));
                    const float tau_c = RL(TAUp[jp][1], la);
                    const float col_c = RL(CVp[jp][1], la);
                    C[a][0] = __fmaf_rn(-CVp[jp][0], tau_c,
                              __fmaf_rn(TAUp[jp][0], col_c, C[a][0]));
                    C[a][1] = __fmaf_rn(-CVp[jp][1], tau_c,
                              __fmaf_rn(TAUp[jp][1], col_c, C[a][1]));
                }
            }
        }
        float TAU[4][2], CV[4][2];
#pragma unroll
        for (int j = 0; j < 4; ++j) {
            const int k = 8 * Pn + 2 * j;
            const float piv = RL(R[j][1], 4 * Pn + j);
            pf = __fmul_rn(pf, piv);          // step order
            TAU[j][0] = (g0 > k + 1) ? __fdiv_rn(R[j][0], piv) : 0.0f;
            TAU[j][1] = (g1 > k + 1) ? __fdiv_rn(R[j][1], piv) : 0.0f;
            CV[j][0]  = (g0 > k + 1) ? C[j][0] : 0.0f;
            CV[j][1]  = (g1 > k + 1) ? C[j][1] : 0.0f;
            *(float2*)&tauLDS[sv][j][g0] = make_float2(TAU[j][0], TAU[j][1]);
            *(float2*)&colLDS[sv][j][g0] = make_float2(CV[j][0], CV[j][1]);
#pragma unroll
            for (int j2 = j + 1; j2 < 4; ++j2) {
                const int ls = 4 * Pn + j2;
                const float tau_r = RL(TAU[j][0], ls);
                const float col_r = RL(CV[j][0], ls);
                R[j2][0] = __fmaf_rn(-col_r, TAU[j][0],
                           __fmaf_rn(tau_r, CV[j][0], R[j2][0]));
                R[j2][1] = __fmaf_rn(-col_r, TAU[j][1],
                           __fmaf_rn(tau_r, CV[j][1], R[j2][1]));
                const float tau_c = RL(TAU[j][1], ls);
                const float col_c = RL(CV[j][1], ls);
                C[j2][0] = __fmaf_rn(-CV[j][0], tau_c,
                           __fmaf_rn(TAU[j][0], col_c, C[j2][0]));
                C[j2][1] = __fmaf_rn(-CV[j][1], tau_c,
                           __fmaf_rn(TAU[j][1], col_c, C[j2][1]));
            }
        }
#pragma unroll
        for (int j = 0; j < 4; ++j) {
            TAUp[j][0] = TAU[j][0]; TAUp[j][1] = TAU[j][1];
            CVp[j][0]  = CV[j][0];  CVp[j][1]  = CV[j][1];
        }
    };

    // ---- prologue: crew computes panel 0 from raw staged vectors ----
    if (wave == 0) crew(0, false);
    __syncthreads();

    // ---- 15 windows, ONE barrier each: bulk panel P || crew panel P+1 ----
    for (int P = 0; P < 15; ++P) {
        if (wave >= 1 && 2 * wave > P) {
            const int sp = P & 1;
            // batch ALL 24 LDS vector loads upfront — latencies overlap
            float4 trv[4], crv[4], t0v[4], t1v[4], c0v[4], c1v[4];
#pragma unroll
            for (int j = 0; j < 4; ++j) {
                trv[j] = *(const float4*)&tauLDS[sp][j][row0];
                crv[j] = *(const float4*)&colLDS[sp][j][row0];
                t0v[j] = *(const float4*)&tauLDS[sp][j][col0];
                t1v[j] = *(const float4*)&tauLDS[sp][j][col0 + 4];
                c0v[j] = *(const float4*)&colLDS[sp][j][col0];
                c1v[j] = *(const float4*)&colLDS[sp][j][col0 + 4];
            }
#pragma unroll
            for (int j = 0; j < 4; ++j) {
                const float tr[4] = {trv[j].x, trv[j].y, trv[j].z, trv[j].w};
                const float cr[4] = {crv[j].x, crv[j].y, crv[j].z, crv[j].w};
                v2f tc2[4], cc2[4];
                tc2[0].x = t0v[j].x; tc2[0].y = t0v[j].y;
                tc2[1].x = t0v[j].z; tc2[1].y = t0v[j].w;
                tc2[2].x = t1v[j].x; tc2[2].y = t1v[j].y;
                tc2[3].x = t1v[j].z; tc2[3].y = t1v[j].w;
                cc2[0].x = c0v[j].x; cc2[0].y = c0v[j].y;
                cc2[1].x = c0v[j].z; cc2[1].y = c0v[j].w;
                cc2[2].x = c1v[j].x; cc2[2].y = c1v[j].y;
                cc2[3].x = c1v[j].z; cc2[3].y = c1v[j].w;
#pragma unroll
                for (int a = 0; a < 4; ++a) {
                    const v2f trs  = splat2(tr[a]);
                    const v2f ncrs = splat2(-cr[a]);
#pragma unroll
                    for (int c2 = 0; c2 < 4; ++c2) {
                        A2[a][c2] = FMA2(ncrs, tc2[c2],
                                    FMA2(trs, cc2[c2], A2[a][c2]));
                    }
                }
            }
            if (P <= 13) stage(P + 2, P & 1);   // updated through P
        }
        if (wave == 0) crew(P + 1, true);       // panels 1..15
        __syncthreads();
    }

    if (t == 0) out[b] = pf;
}

extern "C" void kernel_launch(void* const* d_in, const int* in_sizes, int n_in,
                              void* d_out, int out_size, void* d_ws, size_t ws_size,
                              hipStream_t stream) {
    const float* x = (const float*)d_in[0];   // [128*128]
    const float* F = (const float*)d_in[1];   // [32640]
    float* out     = (float*)d_out;           // [128]
    (void)in_sizes; (void)n_in; (void)out_size; (void)d_ws; (void)ws_size;

    pfaffian_kernel<<<128, 512, 0, stream>>>(x, F, out);
}

// Round 16
// 76.178 us; speedup vs baseline: 1.0462x; 1.0144x over previous
//
#include <hip/hip_runtime.h>

// Pfaffian of 128 gathered 128x128 skew-symmetric f32 matrices, Parlett-Reid
// LTL^T. One 512-thread block per matrix. r13 look-ahead panel pipeline
// (best measured: 76.1us bench) + POFF bank-conflict padding (the single
// change this round; r11-r15 ran unpadded at 580k conflict-cycles vs r9's
// 322k with padding — ~280 cyc/window of pure LDS stall).
//
// NUMERICS LEDGER (rounds 0-15): np ref is the XLA-CPU f32 trajectory:
//     tmp = fma(tau_r, col_c, A);  A' = fma(-col_r, tau_c, tmp)
// tau = __fdiv_rn(row_k, piv), pf = __fmul_rn in step order. Rounds 5-15
// PASSED with absmax 0.0234375 (bit-stable fingerprint). Dead indices
// staged/published as exact 0.0f -> identity FMAs on never-read entries.
// POFF is layout-only: same values, same ops, same order.
//
// POFF safety: all float2/float4 accesses start at even/4-/8-aligned
// element indices, which never straddle a 32-float pad block, so vector
// accesses stay contiguous in the padded array (size 144 >= POFF(127)+1).
//
// PERF LEDGER: r8 50.6us -> r9 47 -> r11 41 -> r12 panels ~29 -> r13
// look-ahead ~25.6 (BEST) -> r14 pk-everywhere 79.7 bench (regressed) ->
// r15 crew-scalar+batch+setprio 77.3 (neutral). r16 = r13 + POFF only.

#define POFF(i) ((i) + (((i) >> 5) << 2))   // 4-float pad every 32 floats
#define RL(v, l) __int_as_float(__builtin_amdgcn_readlane(__float_as_int(v), (l)))

__global__ __launch_bounds__(512) void pfaffian_kernel(
    const float* __restrict__ x,    // [128, 128]
    const float* __restrict__ F,    // [32640] packed strict lower tri of 256x256
    float* __restrict__ out)        // [128]
{
    const int b    = blockIdx.x;
    const int t    = threadIdx.x;
    const int lane = t & 63;
    const int wave = t >> 6;        // 0..7

    __shared__ int idx_sh[128];
    __shared__ int wtot[4];
    __shared__ __align__(16) float tauLDS[2][4][144];
    __shared__ __align__(16) float colLDS[2][4][144];
    __shared__ __align__(16) float rS[2][4][144];   // panel row vecs k0,k0+2,k0+4,k0+6
    __shared__ __align__(16) float cS[2][4][144];   // panel col vecs k0+1,+3,+5,+7

    // ---- occupancy -> sorted index list (certified r0-r15) ----
    if (t < 256) {
        const float xv  = x[b * 128 + (t & 127)];
        const bool  pos = xv > 0.0f;
        const bool  o   = (t < 128) ? pos : !pos;
        const unsigned long long mm = __ballot(o);
        const int rank = __popcll(mm & ((1ull << lane) - 1ull));
        if (lane == 63) wtot[wave] = rank + (o ? 1 : 0);
        __syncthreads();
        int off = 0;
#pragma unroll
        for (int w = 0; w < 4; ++w)
            if (w < wave) off += wtot[w];
        if (o) idx_sh[off + rank] = t;
    } else {
        __syncthreads();   // matches the barrier inside the t<256 branch
    }
    __syncthreads();

    // ---- 4x8 block ownership ----
    const int rg   = t >> 4;        // rows [rg*4, rg*4+4)
    const int cg   = t & 15;        // cols [cg*8, cg*8+8)
    const int row0 = rg << 2;
    const int col0 = cg << 3;
    const int prow = POFF(row0);    // padded offsets (vectors never straddle pads)
    const int pcol = POFF(col0);

    int ri[4], ci[8];
#pragma unroll
    for (int a = 0; a < 4; ++a) ri[a] = idx_sh[row0 + a];
#pragma unroll
    for (int c = 0; c < 8; ++c) ci[c] = idx_sh[col0 + c];

    float A[4][8];
#pragma unroll
    for (int a = 0; a < 4; ++a) {
        const int ii = ri[a];
#pragma unroll
        for (int c = 0; c < 8; ++c) {
            const int jj = ci[c];
            const int hi = ii > jj ? ii : jj;
            const int lo = ii > jj ? jj : ii;
            float v = (ii == jj) ? 0.0f : F[(hi * (hi - 1)) / 2 + lo];
            A[a][c] = (ii < jj) ? -v : v;
        }
    }

    // stage panel Pn (rgbase = 2*Pn, cgbase = Pn) into set st
    auto stage = [&](int Pn, int st) {
        const int rgbase = 2 * Pn;
        if (rg == rgbase) {
            *(float4*)&rS[st][0][pcol]     = make_float4(A[0][0], A[0][1], A[0][2], A[0][3]);
            *(float4*)&rS[st][0][pcol + 4] = make_float4(A[0][4], A[0][5], A[0][6], A[0][7]);
            *(float4*)&rS[st][1][pcol]     = make_float4(A[2][0], A[2][1], A[2][2], A[2][3]);
            *(float4*)&rS[st][1][pcol + 4] = make_float4(A[2][4], A[2][5], A[2][6], A[2][7]);
        }
        if (rg == rgbase + 1) {
            *(float4*)&rS[st][2][pcol]     = make_float4(A[0][0], A[0][1], A[0][2], A[0][3]);
            *(float4*)&rS[st][2][pcol + 4] = make_float4(A[0][4], A[0][5], A[0][6], A[0][7]);
            *(float4*)&rS[st][3][pcol]     = make_float4(A[2][0], A[2][1], A[2][2], A[2][3]);
            *(float4*)&rS[st][3][pcol + 4] = make_float4(A[2][4], A[2][5], A[2][6], A[2][7]);
        }
        if (cg == Pn) {
            *(float4*)&cS[st][0][prow] = make_float4(A[0][1], A[1][1], A[2][1], A[3][1]);
            *(float4*)&cS[st][1][prow] = make_float4(A[0][3], A[1][3], A[2][3], A[3][3]);
            *(float4*)&cS[st][2][prow] = make_float4(A[0][5], A[1][5], A[2][5], A[3][5]);
            *(float4*)&cS[st][3][prow] = make_float4(A[0][7], A[1][7], A[2][7], A[3][7]);
        }
    };
    stage(0, 0);   // panel 0 raw
    stage(1, 1);   // panel 1 raw
    __syncthreads();

    float pf = 1.0f;
    float TAUp[4][2], CVp[4][2];   // crew: previous panel's tau/col (registers)

    // crew for panel Pn: pre-update with panel Pn-1 (if pre), chain, publish
    auto crew = [&](int Pn, bool pre) {
        const int sv = Pn & 1;
        const int g0 = lane << 1;
        const int g1 = g0 + 1;
        const int pg = POFF(g0);   // even pair never straddles a pad block
        float R[4][2], C[4][2];
#pragma unroll
        for (int j = 0; j < 4; ++j) {
            const float2 rv = *(const float2*)&rS[sv][j][pg];
            const float2 cv = *(const float2*)&cS[sv][j][pg];
            R[j][0] = rv.x; R[j][1] = rv.y;
            C[j][0] = cv.x; C[j][1] = cv.y;
        }
        if (pre) {
            // apply panel Pn-1 (TAUp/CVp) — bit-exact with bulk's schedule
#pragma unroll
            for (int jp = 0; jp < 4; ++jp) {
#pragma unroll
                for (int a = 0; a < 4; ++a) {
                    const int la = 4 * Pn + a;   // lane of row 8Pn+2a / col +1
                    const float tau_r = RL(TAUp[jp][0], la);
                    const float col_r = RL(CVp[jp][0], la);
                    R[a][0] = __fmaf_rn(-col_r, TAUp[jp][0],
                              __fmaf_rn(tau_r, CVp[jp][0], R[a][0]));
                    R[a][1] = __fmaf_rn(-col_r, TAUp[jp][1],
                              __fmaf_rn(tau_r, CVp[jp][1], R[a][1]));
                    const float tau_c = RL(TAUp[jp][1], la);
                    const float col_c = RL(CVp[jp][1], la);
                    C[a][0] = __fmaf_rn(-CVp[jp][0], tau_c,
                              __fmaf_rn(TAUp[jp][0], col_c, C[a][0]));
                    C[a][1] = __fmaf_rn(-CVp[jp][1], tau_c,
                              __fmaf_rn(TAUp[jp][1], col_c, C[a][1]));
                }
            }
        }
        float TAU[4][2], CV[4][2];
#pragma unroll
        for (int j = 0; j < 4; ++j) {
            const int k = 8 * Pn + 2 * j;
            const float piv = RL(R[j][1], 4 * Pn + j);
            pf = __fmul_rn(pf, piv);          // step order
            TAU[j][0] = (g0 > k + 1) ? __fdiv_rn(R[j][0], piv) : 0.0f;
            TAU[j][1] = (g1 > k + 1) ? __fdiv_rn(R[j][1], piv) : 0.0f;
            CV[j][0]  = (g0 > k + 1) ? C[j][0] : 0.0f;
            CV[j][1]  = (g1 > k + 1) ? C[j][1] : 0.0f;
            *(float2*)&tauLDS[sv][j][pg] = make_float2(TAU[j][0], TAU[j][1]);
            *(float2*)&colLDS[sv][j][pg] = make_float2(CV[j][0], CV[j][1]);
            // look-ahead: update later panel vectors with step j
#pragma unroll
            for (int j2 = j + 1; j2 < 4; ++j2) {
                const int ls = 4 * Pn + j2;
                const float tau_r = RL(TAU[j][0], ls);
                const float col_r = RL(CV[j][0], ls);
                R[j2][0] = __fmaf_rn(-col_r, TAU[j][0],
                           __fmaf_rn(tau_r, CV[j][0], R[j2][0]));
                R[j2][1] = __fmaf_rn(-col_r, TAU[j][1],
                           __fmaf_rn(tau_r, CV[j][1], R[j2][1]));
                const float tau_c = RL(TAU[j][1], ls);
                const float col_c = RL(CV[j][1], ls);
                C[j2][0] = __fmaf_rn(-CV[j][0], tau_c,
                           __fmaf_rn(TAU[j][0], col_c, C[j2][0]));
                C[j2][1] = __fmaf_rn(-CV[j][1], tau_c,
                           __fmaf_rn(TAU[j][1], col_c, C[j2][1]));
            }
        }
#pragma unroll
        for (int j = 0; j < 4; ++j) {
            TAUp[j][0] = TAU[j][0]; TAUp[j][1] = TAU[j][1];
            CVp[j][0]  = CV[j][0];  CVp[j][1]  = CV[j][1];
        }
    };

    // ---- prologue: crew computes panel 0 from raw staged vectors ----
    if (wave == 0) crew(0, false);
    __syncthreads();

    // ---- 15 windows, ONE barrier each: bulk panel P || crew panel P+1 ----
    for (int P = 0; P < 15; ++P) {
        if (wave >= 1 && 2 * wave > P) {
            const int sp = P & 1;
#pragma unroll
            for (int j = 0; j < 4; ++j) {
                const float4 trv = *(const float4*)&tauLDS[sp][j][prow];
                const float4 crv = *(const float4*)&colLDS[sp][j][prow];
                const float4 t0v = *(const float4*)&tauLDS[sp][j][pcol];
                const float4 t1v = *(const float4*)&tauLDS[sp][j][pcol + 4];
                const float4 c0v = *(const float4*)&colLDS[sp][j][pcol];
                const float4 c1v = *(const float4*)&colLDS[sp][j][pcol + 4];
                const float tr[4] = {trv.x, trv.y, trv.z, trv.w};
                const float cr[4] = {crv.x, crv.y, crv.z, crv.w};
                const float tc[8] = {t0v.x, t0v.y, t0v.z, t0v.w,
                                     t1v.x, t1v.y, t1v.z, t1v.w};
                const float cc[8] = {c0v.x, c0v.y, c0v.z, c0v.w,
                                     c1v.x, c1v.y, c1v.z, c1v.w};
#pragma unroll
                for (int a = 0; a < 4; ++a) {
#pragma unroll
                    for (int c = 0; c < 8; ++c) {
                        A[a][c] = __fmaf_rn(-cr[a], tc[c],
                                  __fmaf_rn(tr[a], cc[c], A[a][c]));
                    }
                }
            }
            if (P <= 13) stage(P + 2, P & 1);   // updated through P
        }
        if (wave == 0) crew(P + 1, true);       // panels 1..15
        __syncthreads();
    }

    if (t == 0) out[b] = pf;
}

extern "C" void kernel_launch(void* const* d_in, const int* in_sizes, int n_in,
                              void* d_out, int out_size, void* d_ws, size_t ws_size,
                              hipStream_t stream) {
    const float* x = (const float*)d_in[0];   // [128*128]
    const float* F = (const float*)d_in[1];   // [32640]
    float* out     = (float*)d_out;           // [128]
    (void)in_sizes; (void)n_in; (void)out_size; (void)d_ws; (void)ws_size;

    pfaffian_kernel<<<128, 512, 0, stream>>>(x, F, out);
}

// Round 17
// 75.642 us; speedup vs baseline: 1.0536x; 1.0071x over previous
//
#include <hip/hip_runtime.h>

// Pfaffian of 128 gathered 128x128 skew-symmetric f32 matrices, Parlett-Reid
// LTL^T. One 512-thread block per matrix. r13 look-ahead panel pipeline +
// POFF padding (r16) + THIS ROUND: crew pre-update reads panel Pn-1's
// tau/col via batched same-address LDS broadcasts (they're already in
// tauLDS/colLDS[sv^1] from last window) instead of 64 serialized
// v_readlane's — removes the VALU->SGPR->VALU hazard chain from the crew
// pole. Identical values, identical fma sequence -> bit-identical result.
//
// NUMERICS LEDGER (rounds 0-16): np ref is the XLA-CPU f32 trajectory:
//     tmp = fma(tau_r, col_c, A);  A' = fma(-col_r, tau_c, tmp)
// tau = __fdiv_rn(row_k, piv), pf = __fmul_rn in step order. Rounds 5-16
// PASSED with absmax 0.0234375 (bit-stable fingerprint). Dead indices
// staged/published as exact 0.0f -> identity FMAs on never-read entries.
//
// STRUCTURAL NOTE: the crew pre-update is irreducible — staging must be
// 2-ahead (1-ahead fresh staging would race crew in the same window), so
// the tau-extractor must itself apply the preceding panel. Only its cost
// can shrink (this round: hazard removal).
//
// PERF LEDGER: r8 50.6us -> r9 47 -> r11 41 -> r12 panels ~29 -> r13
// look-ahead ~25.6 (bench 76.1, BEST) -> r14 pk-everywhere 79.7 (regr) ->
// r15 batch+setprio 77.3 (neutral) -> r16 +POFF 76.2 (neutral; conflicts
// were latency-hidden). r17 = r16 + LDS-broadcast crew pre-update.

#define POFF(i) ((i) + (((i) >> 5) << 2))   // 4-float pad every 32 floats
#define RL(v, l) __int_as_float(__builtin_amdgcn_readlane(__float_as_int(v), (l)))

__global__ __launch_bounds__(512) void pfaffian_kernel(
    const float* __restrict__ x,    // [128, 128]
    const float* __restrict__ F,    // [32640] packed strict lower tri of 256x256
    float* __restrict__ out)        // [128]
{
    const int b    = blockIdx.x;
    const int t    = threadIdx.x;
    const int lane = t & 63;
    const int wave = t >> 6;        // 0..7

    __shared__ int idx_sh[128];
    __shared__ int wtot[4];
    __shared__ __align__(16) float tauLDS[2][4][144];
    __shared__ __align__(16) float colLDS[2][4][144];
    __shared__ __align__(16) float rS[2][4][144];   // panel row vecs k0,k0+2,k0+4,k0+6
    __shared__ __align__(16) float cS[2][4][144];   // panel col vecs k0+1,+3,+5,+7

    // ---- occupancy -> sorted index list (certified r0-r16) ----
    if (t < 256) {
        const float xv  = x[b * 128 + (t & 127)];
        const bool  pos = xv > 0.0f;
        const bool  o   = (t < 128) ? pos : !pos;
        const unsigned long long mm = __ballot(o);
        const int rank = __popcll(mm & ((1ull << lane) - 1ull));
        if (lane == 63) wtot[wave] = rank + (o ? 1 : 0);
        __syncthreads();
        int off = 0;
#pragma unroll
        for (int w = 0; w < 4; ++w)
            if (w < wave) off += wtot[w];
        if (o) idx_sh[off + rank] = t;
    } else {
        __syncthreads();   // matches the barrier inside the t<256 branch
    }
    __syncthreads();

    // ---- 4x8 block ownership ----
    const int rg   = t >> 4;        // rows [rg*4, rg*4+4)
    const int cg   = t & 15;        // cols [cg*8, cg*8+8)
    const int row0 = rg << 2;
    const int col0 = cg << 3;
    const int prow = POFF(row0);
    const int pcol = POFF(col0);

    int ri[4], ci[8];
#pragma unroll
    for (int a = 0; a < 4; ++a) ri[a] = idx_sh[row0 + a];
#pragma unroll
    for (int c = 0; c < 8; ++c) ci[c] = idx_sh[col0 + c];

    float A[4][8];
#pragma unroll
    for (int a = 0; a < 4; ++a) {
        const int ii = ri[a];
#pragma unroll
        for (int c = 0; c < 8; ++c) {
            const int jj = ci[c];
            const int hi = ii > jj ? ii : jj;
            const int lo = ii > jj ? jj : ii;
            float v = (ii == jj) ? 0.0f : F[(hi * (hi - 1)) / 2 + lo];
            A[a][c] = (ii < jj) ? -v : v;
        }
    }

    // stage panel Pn (rgbase = 2*Pn, cgbase = Pn) into set st
    auto stage = [&](int Pn, int st) {
        const int rgbase = 2 * Pn;
        if (rg == rgbase) {
            *(float4*)&rS[st][0][pcol]     = make_float4(A[0][0], A[0][1], A[0][2], A[0][3]);
            *(float4*)&rS[st][0][pcol + 4] = make_float4(A[0][4], A[0][5], A[0][6], A[0][7]);
            *(float4*)&rS[st][1][pcol]     = make_float4(A[2][0], A[2][1], A[2][2], A[2][3]);
            *(float4*)&rS[st][1][pcol + 4] = make_float4(A[2][4], A[2][5], A[2][6], A[2][7]);
        }
        if (rg == rgbase + 1) {
            *(float4*)&rS[st][2][pcol]     = make_float4(A[0][0], A[0][1], A[0][2], A[0][3]);
            *(float4*)&rS[st][2][pcol + 4] = make_float4(A[0][4], A[0][5], A[0][6], A[0][7]);
            *(float4*)&rS[st][3][pcol]     = make_float4(A[2][0], A[2][1], A[2][2], A[2][3]);
            *(float4*)&rS[st][3][pcol + 4] = make_float4(A[2][4], A[2][5], A[2][6], A[2][7]);
        }
        if (cg == Pn) {
            *(float4*)&cS[st][0][prow] = make_float4(A[0][1], A[1][1], A[2][1], A[3][1]);
            *(float4*)&cS[st][1][prow] = make_float4(A[0][3], A[1][3], A[2][3], A[3][3]);
            *(float4*)&cS[st][2][prow] = make_float4(A[0][5], A[1][5], A[2][5], A[3][5]);
            *(float4*)&cS[st][3][prow] = make_float4(A[0][7], A[1][7], A[2][7], A[3][7]);
        }
    };
    stage(0, 0);   // panel 0 raw
    stage(1, 1);   // panel 1 raw
    __syncthreads();

    float pf = 1.0f;

    // crew for panel Pn: pre-update with panel Pn-1 (if pre), chain, publish.
    // Pre-update reads panel Pn-1's tau/col from tauLDS/colLDS[sv^1] via
    // batched same-address (broadcast) LDS reads — the global indices needed
    // are 8Pn..8Pn+7, contiguous, never straddling a POFF pad block.
    auto crew = [&](int Pn, bool pre) {
        const int sv = Pn & 1;
        const int g0 = lane << 1;
        const int g1 = g0 + 1;
        const int pg = POFF(g0);
        float R[4][2], C[4][2];
#pragma unroll
        for (int j = 0; j < 4; ++j) {
            const float2 rv = *(const float2*)&rS[sv][j][pg];
            const float2 cv = *(const float2*)&cS[sv][j][pg];
            R[j][0] = rv.x; R[j][1] = rv.y;
            C[j][0] = cv.x; C[j][1] = cv.y;
        }
        if (pre) {
            const int svp  = sv ^ 1;
            const int base = POFF(8 * Pn);   // 8Pn..8Pn+7 within one pad block
            float4 Tq[4][2], Cq[4][2];
#pragma unroll
            for (int jp = 0; jp < 4; ++jp) {   // batched: latencies overlap
                Tq[jp][0] = *(const float4*)&tauLDS[svp][jp][base];
                Tq[jp][1] = *(const float4*)&tauLDS[svp][jp][base + 4];
                Cq[jp][0] = *(const float4*)&colLDS[svp][jp][base];
                Cq[jp][1] = *(const float4*)&colLDS[svp][jp][base + 4];
            }
#pragma unroll
            for (int jp = 0; jp < 4; ++jp) {
                const float trA[4] = {Tq[jp][0].x, Tq[jp][0].z, Tq[jp][1].x, Tq[jp][1].z};
                const float crA[4] = {Cq[jp][0].x, Cq[jp][0].z, Cq[jp][1].x, Cq[jp][1].z};
                const float tcA[4] = {Tq[jp][0].y, Tq[jp][0].w, Tq[jp][1].y, Tq[jp][1].w};
                const float ccA[4] = {Cq[jp][0].y, Cq[jp][0].w, Cq[jp][1].y, Cq[jp][1].w};
#pragma unroll
                for (int a = 0; a < 4; ++a) {
                    // identical values & fma pairs as the old readlane form
                    R[a][0] = __fmaf_rn(-crA[a], tauLDS[svp][jp][pg] * 0.0f + /*unused*/ 0.0f + 0.0f, R[a][0]);
                    R[a][0] = R[a][0]; // (placeholder removed below)
                }
#pragma unroll
                for (int a = 0; a < 4; ++a) {
                    const float tau_r = trA[a], col_r = crA[a];
                    R[a][0] = __fmaf_rn(-col_r, /*TAUp[jp][0] elem g0*/ 0.0f, R[a][0]);
                }
            }
            // --- NOTE: the two loops above are replaced by the real code: ---
        }
        // (real pre-update below; the stub above is never compiled in)
        float TAU[4][2], CV[4][2];
#pragma unroll
        for (int j = 0; j < 4; ++j) {
            const int k = 8 * Pn + 2 * j;
            const float piv = RL(R[j][1], 4 * Pn + j);
            pf = __fmul_rn(pf, piv);          // step order
            TAU[j][0] = (g0 > k + 1) ? __fdiv_rn(R[j][0], piv) : 0.0f;
            TAU[j][1] = (g1 > k + 1) ? __fdiv_rn(R[j][1], piv) : 0.0f;
            CV[j][0]  = (g0 > k + 1) ? C[j][0] : 0.0f;
            CV[j][1]  = (g1 > k + 1) ? C[j][1] : 0.0f;
            *(float2*)&tauLDS[sv][j][pg] = make_float2(TAU[j][0], TAU[j][1]);
            *(float2*)&colLDS[sv][j][pg] = make_float2(CV[j][0], CV[j][1]);
#pragma unroll
            for (int j2 = j + 1; j2 < 4; ++j2) {
                const int ls = 4 * Pn + j2;
                const float tau_r = RL(TAU[j][0], ls);
                const float col_r = RL(CV[j][0], ls);
                R[j2][0] = __fmaf_rn(-col_r, TAU[j][0],
                           __fmaf_rn(tau_r, CV[j][0], R[j2][0]));
                R[j2][1] = __fmaf_rn(-col_r, TAU[j][1],
                           __fmaf_rn(tau_r, CV[j][1], R[j2][1]));
                const float tau_c = RL(TAU[j][1], ls);
                const float col_c = RL(CV[j][1], ls);
                C[j2][0] = __fmaf_rn(-CV[j][0], tau_c,
                           __fmaf_rn(TAU[j][0], col_c, C[j2][0]));
                C[j2][1] = __fmaf_rn(-CV[j][1], tau_c,
                           __fmaf_rn(TAU[j][1], col_c, C[j2][1]));
            }
        }
        (void)TAU; (void)CV;
    };
    (void)crew;

    // ======================================================================
    // The lambda above got garbled during editing; the ACTUAL crew used is
    // crew2 below (clean implementation). crew/stage data layout unchanged.
    // ======================================================================
    auto crew2 = [&](int Pn, bool pre) {
        const int sv = Pn & 1;
        const int g0 = lane << 1;
        const int g1 = g0 + 1;
        const int pg = POFF(g0);
        float R[4][2], C[4][2];
#pragma unroll
        for (int j = 0; j < 4; ++j) {
            const float2 rv = *(const float2*)&rS[sv][j][pg];
            const float2 cv = *(const float2*)&cS[sv][j][pg];
            R[j][0] = rv.x; R[j][1] = rv.y;
            C[j][0] = cv.x; C[j][1] = cv.y;
        }
        if (pre) {
            const int svp  = sv ^ 1;
            const int base = POFF(8 * Pn);   // contiguous, inside one pad block
            float4 Tq[4][2], Cq[4][2];
#pragma unroll
            for (int jp = 0; jp < 4; ++jp) {   // batched broadcast loads
                Tq[jp][0] = *(const float4*)&tauLDS[svp][jp][base];
                Tq[jp][1] = *(const float4*)&tauLDS[svp][jp][base + 4];
                Cq[jp][0] = *(const float4*)&colLDS[svp][jp][base];
                Cq[jp][1] = *(const float4*)&colLDS[svp][jp][base + 4];
            }
#pragma unroll
            for (int jp = 0; jp < 4; ++jp) {
                const float trA[4] = {Tq[jp][0].x, Tq[jp][0].z, Tq[jp][1].x, Tq[jp][1].z};
                const float crA[4] = {Cq[jp][0].x, Cq[jp][0].z, Cq[jp][1].x, Cq[jp][1].z};
                const float tcA[4] = {Tq[jp][0].y, Tq[jp][0].w, Tq[jp][1].y, Tq[jp][1].w};
                const float ccA[4] = {Cq[jp][0].y, Cq[jp][0].w, Cq[jp][1].y, Cq[jp][1].w};
                // TAUp[jp] at this lane == tau of panel Pn-1 step jp at
                // indices (g0,g1) == tauLDS[svp][jp][pg..pg+1]; same for CVp.
                const float2 tpv = *(const float2*)&tauLDS[svp][jp][pg];
                const float2 cpv = *(const float2*)&colLDS[svp][jp][pg];
#pragma unroll
                for (int a = 0; a < 4; ++a) {
                    const float tau_r = trA[a];   // == RL(TAUp[jp][0], la)
                    const float col_r = crA[a];   // == RL(CVp[jp][0], la)
                    R[a][0] = __fmaf_rn(-col_r, tpv.x,
                              __fmaf_rn(tau_r, cpv.x, R[a][0]));
                    R[a][1] = __fmaf_rn(-col_r, tpv.y,
                              __fmaf_rn(tau_r, cpv.y, R[a][1]));
                    const float tau_c = tcA[a];   // == RL(TAUp[jp][1], la)
                    const float col_c = ccA[a];   // == RL(CVp[jp][1], la)
                    C[a][0] = __fmaf_rn(-cpv.x, tau_c,
                              __fmaf_rn(tpv.x, col_c, C[a][0]));
                    C[a][1] = __fmaf_rn(-cpv.y, tau_c,
                              __fmaf_rn(tpv.y, col_c, C[a][1]));
                }
            }
        }
        float TAU[4][2], CV[4][2];
#pragma unroll
        for (int j = 0; j < 4; ++j) {
            const int k = 8 * Pn + 2 * j;
            const float piv = RL(R[j][1], 4 * Pn + j);
            pf = __fmul_rn(pf, piv);          // step order
            TAU[j][0] = (g0 > k + 1) ? __fdiv_rn(R[j][0], piv) : 0.0f;
            TAU[j][1] = (g1 > k + 1) ? __fdiv_rn(R[j][1], piv) : 0.0f;
            CV[j][0]  = (g0 > k + 1) ? C[j][0] : 0.0f;
            CV[j][1]  = (g1 > k + 1) ? C[j][1] : 0.0f;
            *(float2*)&tauLDS[sv][j][pg] = make_float2(TAU[j][0], TAU[j][1]);
            *(float2*)&colLDS[sv][j][pg] = make_float2(CV[j][0], CV[j][1]);
#pragma unroll
            for (int j2 = j + 1; j2 < 4; ++j2) {
                const int ls = 4 * Pn + j2;
                const float tau_r = RL(TAU[j][0], ls);
                const float col_r = RL(CV[j][0], ls);
                R[j2][0] = __fmaf_rn(-col_r, TAU[j][0],
                           __fmaf_rn(tau_r, CV[j][0], R[j2][0]));
                R[j2][1] = __fmaf_rn(-col_r, TAU[j][1],
                           __fmaf_rn(tau_r, CV[j][1], R[j2][1]));
                const float tau_c = RL(TAU[j][1], ls);
                const float col_c = RL(CV[j][1], ls);
                C[j2][0] = __fmaf_rn(-CV[j][0], tau_c,
                           __fmaf_rn(TAU[j][0], col_c, C[j2][0]));
                C[j2][1] = __fmaf_rn(-CV[j][1], tau_c,
                           __fmaf_rn(TAU[j][1], col_c, C[j2][1]));
            }
        }
    };

    // ---- prologue: crew computes panel 0 from raw staged vectors ----
    if (wave == 0) crew2(0, false);
    __syncthreads();

    // ---- 15 windows, ONE barrier each: bulk panel P || crew panel P+1 ----
    for (int P = 0; P < 15; ++P) {
        if (wave >= 1 && 2 * wave > P) {
            const int sp = P & 1;
#pragma unroll
            for (int j = 0; j < 4; ++j) {
                const float4 trv = *(const float4*)&tauLDS[sp][j][prow];
                const float4 crv = *(const float4*)&colLDS[sp][j][prow];
                const float4 t0v = *(const float4*)&tauLDS[sp][j][pcol];
                const float4 t1v = *(const float4*)&tauLDS[sp][j][pcol + 4];
                const float4 c0v = *(const float4*)&colLDS[sp][j][pcol];
                const float4 c1v = *(const float4*)&colLDS[sp][j][pcol + 4];
                const float tr[4] = {trv.x, trv.y, trv.z, trv.w};
                const float cr[4] = {crv.x, crv.y, crv.z, crv.w};
                const float tc[8] = {t0v.x, t0v.y, t0v.z, t0v.w,
                                     t1v.x, t1v.y, t1v.z, t1v.w};
                const float cc[8] = {c0v.x, c0v.y, c0v.z, c0v.w,
                                     c1v.x, c1v.y, c1v.z, c1v.w};
#pragma unroll
                for (int a = 0; a < 4; ++a) {
#pragma unroll
                    for (int c = 0; c < 8; ++c) {
                        A[a][c] = __fmaf_rn(-cr[a], tc[c],
                                  __fmaf_rn(tr[a], cc[c], A[a][c]));
                    }
                }
            }
            if (P <= 13) stage(P + 2, P & 1);   // updated through P
        }
        if (wave == 0) crew2(P + 1, true);      // panels 1..15
        __syncthreads();
    }

    if (t == 0) out[b] = pf;
}

extern "C" void kernel_launch(void* const* d_in, const int* in_sizes, int n_in,
                              void* d_out, int out_size, void* d_ws, size_t ws_size,
                              hipStream_t stream) {
    const float* x = (const float*)d_in[0];   // [128*128]
    const float* F = (const float*)d_in[1];   // [32640]
    float* out     = (float*)d_out;           // [128]
    (void)in_sizes; (void)n_in; (void)out_size; (void)d_ws; (void)ws_size;

    pfaffian_kernel<<<128, 512, 0, stream>>>(x, F, out);
}